// Round 12
// baseline (335.150 us; speedup 1.0000x reference)
//
#include <hip/hip_runtime.h>
#include <math.h>

#define K_CODES 512
#define DIM 64
#define NPTS (32 * 4096)   // 131072 points
#define NQ (NPTS * DIM)    // 8388608 quant_out elements
#define BPTS 256           // points per block
#define TAU 2.0e-3f        // rescue margin >> worst-case split-f16 error (~5.5e-4)

typedef _Float16 f16x8 __attribute__((ext_vector_type(8)));
typedef float f32x4 __attribute__((ext_vector_type(4)));

// d_out layout (floats): [quant_out: 8388608][loss: 1][indices-as-float: 131072]
// d_ws layout: [blob: 131072B][shalf: 512 f32]

__global__ void init_kernel(float* __restrict__ loss) { loss[0] = 0.0f; }
__global__ void finalize_kernel(float* __restrict__ loss) {
    loss[0] = 1.2f * loss[0] / 8388608.0f; // (1+BETA)*mean
}

// Fragment-ready split-f16 codebook (identical to r11's proven layout).
__global__ __launch_bounds__(64) void prep_kernel(const float* __restrict__ cb,
                                                  _Float16* __restrict__ blob,
                                                  float* __restrict__ shalfg) {
    int k = blockIdx.x, d = threadIdx.x;
    float e = cb[k * DIM + d];
    _Float16 hi = (_Float16)e;
    _Float16 lo = (_Float16)(e - (float)hi);
    int cf = k >> 4, col = k & 15;
    int q = d >> 5, dd = d & 31, kg = dd >> 3, j = dd & 7;
    size_t base = ((size_t)(cf * 4 + q) * 64 + (kg * 16 + col)) * 8 + j;
    blob[base] = hi;
    blob[base + 2 * 64 * 8] = lo;
    float s = e * e;
#pragma unroll
    for (int m = 32; m; m >>= 1) s += __shfl_xor(s, m);
    if (d == 0) shalfg[k] = 0.5f * s;
}

// 512 blocks x 512 thr (8 waves). Wave = 32 points, scans all 512 codes via
// MFMA on L2-resident frag blob. Near-ties rescued WAVE-PARALLEL in f32.
__global__ __launch_bounds__(512, 4) void vq_main(const float* __restrict__ qin,
                                                  const float* __restrict__ cb,
                                                  const _Float16* __restrict__ blob,
                                                  const float* __restrict__ shalfg,
                                                  float* __restrict__ out,
                                                  float* __restrict__ loss_acc,
                                                  float* __restrict__ idx_out) {
    __shared__ float shs[K_CODES];
    __shared__ int sfinal[BPTS];
    __shared__ float wsum[8];

    const int tid = threadIdx.x, lane = tid & 63, w = tid >> 6;
    const int row16 = lane & 15, kg = lane >> 4;
    const int wp = w * 32;
    const int n0 = blockIdx.x * BPTS;
    const int b = n0 >> 12, hw0 = n0 & 4095;
    const float* qbase = qin + ((size_t)b << 18) + hw0;
    const f16x8* blp = (const f16x8*)blob + lane;

    shs[tid] = shalfg[tid];

    // ---- A-frags in registers (hi/lo split on the fly); 2 row-frags ----
    f16x8 ah0[2], ah1[2], al0[2], al1[2];
#pragma unroll
    for (int rr = 0; rr < 2; ++rr) {
        const float* xb = qbase + (wp + rr * 16 + row16);
#pragma unroll
        for (int j = 0; j < 8; ++j) {
            float xa = xb[(size_t)(kg * 8 + j) << 12];
            float xc = xb[(size_t)(32 + kg * 8 + j) << 12];
            _Float16 ha = (_Float16)xa, hc = (_Float16)xc;
            ah0[rr][j] = ha; al0[rr][j] = (_Float16)(xa - (float)ha);
            ah1[rr][j] = hc; al1[rr][j] = (_Float16)(xc - (float)hc);
        }
    }
    __syncthreads(); // shs ready

    float b1[8], b2[8];
    int k1[8];
#pragma unroll
    for (int sl = 0; sl < 8; ++sl) { b1[sl] = -INFINITY; b2[sl] = -INFINITY; k1[sl] = 0; }

    // software-prefetch B-frags one cf ahead
    f16x8 nb0 = blp[0 * 64], nb1 = blp[1 * 64], nb2v = blp[2 * 64], nb3 = blp[3 * 64];
#pragma unroll 1
    for (int cf = 0; cf < 32; ++cf) {
        f16x8 bh0 = nb0, bh1 = nb1, bL0 = nb2v, bL1 = nb3;
        if (cf + 1 < 32) {
            nb0 = blp[((cf + 1) * 4 + 0) * 64];
            nb1 = blp[((cf + 1) * 4 + 1) * 64];
            nb2v = blp[((cf + 1) * 4 + 2) * 64];
            nb3 = blp[((cf + 1) * 4 + 3) * 64];
        }
        float sh = shs[cf * 16 + row16];
        f32x4 ini = {-sh, -sh, -sh, -sh};
        f32x4 ac0 = ini, ac1 = ini;
        ac0 = __builtin_amdgcn_mfma_f32_16x16x32_f16(ah0[0], bh0, ac0, 0, 0, 0);
        ac1 = __builtin_amdgcn_mfma_f32_16x16x32_f16(ah0[1], bh0, ac1, 0, 0, 0);
        ac0 = __builtin_amdgcn_mfma_f32_16x16x32_f16(ah1[0], bh1, ac0, 0, 0, 0);
        ac1 = __builtin_amdgcn_mfma_f32_16x16x32_f16(ah1[1], bh1, ac1, 0, 0, 0);
        ac0 = __builtin_amdgcn_mfma_f32_16x16x32_f16(al0[0], bh0, ac0, 0, 0, 0);
        ac1 = __builtin_amdgcn_mfma_f32_16x16x32_f16(al0[1], bh0, ac1, 0, 0, 0);
        ac0 = __builtin_amdgcn_mfma_f32_16x16x32_f16(al1[0], bh1, ac0, 0, 0, 0);
        ac1 = __builtin_amdgcn_mfma_f32_16x16x32_f16(al1[1], bh1, ac1, 0, 0, 0);
        ac0 = __builtin_amdgcn_mfma_f32_16x16x32_f16(ah0[0], bL0, ac0, 0, 0, 0);
        ac1 = __builtin_amdgcn_mfma_f32_16x16x32_f16(ah0[1], bL0, ac1, 0, 0, 0);
        ac0 = __builtin_amdgcn_mfma_f32_16x16x32_f16(ah1[0], bL1, ac0, 0, 0, 0);
        ac1 = __builtin_amdgcn_mfma_f32_16x16x32_f16(ah1[1], bL1, ac1, 0, 0, 0);
        int kglob = cf * 16 + row16;
#define UPD(RR, AC)                                               \
        {                                                         \
            _Pragma("unroll") for (int r = 0; r < 4; ++r) {       \
                float s = (AC)[r];                                \
                int sl = (RR) * 4 + r;                            \
                bool c1 = s > b1[sl];                             \
                bool c2 = s > b2[sl];                             \
                b2[sl] = c1 ? b1[sl] : (c2 ? s : b2[sl]);         \
                b1[sl] = c1 ? s : b1[sl];                         \
                k1[sl] = c1 ? kglob : k1[sl];                     \
            }                                                     \
        }
        UPD(0, ac0) UPD(1, ac1)
#undef UPD
    }

    // reduce top-2 across the 16 col-lanes (butterfly -> uniform per group)
#pragma unroll
    for (int m = 1; m <= 8; m <<= 1) {
#pragma unroll
        for (int sl = 0; sl < 8; ++sl) {
            float ob1 = __shfl_xor(b1[sl], m);
            float ob2 = __shfl_xor(b2[sl], m);
            int ok1 = __shfl_xor(k1[sl], m);
            float nb2x = fmaxf(fminf(b1[sl], ob1), fmaxf(b2[sl], ob2));
            bool take = (ob1 > b1[sl]) || (ob1 == b1[sl] && ok1 < k1[sl]);
            b1[sl] = take ? ob1 : b1[sl];
            k1[sl] = take ? ok1 : k1[sl];
            b2[sl] = nb2x;
        }
    }

    // provisional writes + WAVE-PARALLEL rescue of flagged near-ties
#pragma unroll 1
    for (int sl = 0; sl < 8; ++sl) {
        bool fl = (b1[sl] - b2[sl]) < TAU;
        int pt = wp + (sl >> 2) * 16 + kg * 4 + (sl & 3);
        if (row16 == 0 && !fl) {
            sfinal[pt] = k1[sl];
            idx_out[n0 + pt] = (float)k1[sl];
        }
        unsigned long long mask = __ballot(fl && row16 == 0);
        while (mask) {
            int src = __ffsll((long long)mask) - 1;
            mask &= mask - 1;
            int rpt = wp + (sl >> 2) * 16 + ((src >> 4) << 2) + (sl & 3);
            const float* qx = qbase + rpt;
            float x[DIM];
#pragma unroll
            for (int d = 0; d < DIM; ++d) x[d] = qx[(size_t)d << 12]; // uniform
            float bs = -INFINITY;
            int bi = 0;
#pragma unroll 1
            for (int i = 0; i < 8; ++i) { // lane's codes: k = i*64+lane
                int k = i * 64 + lane;
                const float4* c4 = (const float4*)(cb + (size_t)k * DIM);
                float d0 = 0.f, d1 = 0.f, d2 = 0.f, d3 = 0.f;
#pragma unroll
                for (int i2 = 0; i2 < 16; ++i2) {
                    float4 c = c4[i2];
                    d0 = fmaf(x[4 * i2 + 0], c.x, d0);
                    d1 = fmaf(x[4 * i2 + 1], c.y, d1);
                    d2 = fmaf(x[4 * i2 + 2], c.z, d2);
                    d3 = fmaf(x[4 * i2 + 3], c.w, d3);
                }
                float sc = ((d0 + d1) + (d2 + d3)) - shs[k];
                if (sc > bs) { bs = sc; bi = k; } // ascending within lane
            }
#pragma unroll
            for (int m = 1; m < 64; m <<= 1) { // min-k tiebreak => global first-min
                float os = __shfl_xor(bs, m);
                int oi = __shfl_xor(bi, m);
                if (os > bs || (os == bs && oi < bi)) { bs = os; bi = oi; }
            }
            if (lane == 0) {
                sfinal[rpt] = bi;
                idx_out[n0 + rpt] = (float)bi;
            }
        }
    }
    __syncthreads();

    // epilogue: thread t -> point t&255, dim-half t>>8 (32 dims each)
    {
        int p = tid & 255, hh = tid >> 8;
        int ci = sfinal[p];
        const float* crow = cb + (size_t)ci * DIM + hh * 32;
        const float* qrow = qbase + p + ((size_t)(hh * 32) << 12);
        float* orow = out + ((size_t)b << 18) + hw0 + p + ((size_t)(hh * 32) << 12);
        float l0 = 0.f, l1 = 0.f, l2 = 0.f, l3 = 0.f;
#pragma unroll
        for (int d = 0; d < 32; d += 4) {
            float4 v = *(const float4*)(crow + d);
            orow[(size_t)(d + 0) << 12] = v.x;
            orow[(size_t)(d + 1) << 12] = v.y;
            orow[(size_t)(d + 2) << 12] = v.z;
            orow[(size_t)(d + 3) << 12] = v.w;
            float q0 = qrow[(size_t)(d + 0) << 12];
            float q1 = qrow[(size_t)(d + 1) << 12];
            float q2 = qrow[(size_t)(d + 2) << 12];
            float q3 = qrow[(size_t)(d + 3) << 12];
            float e0 = v.x - q0, e1 = v.y - q1, e2 = v.z - q2, e3 = v.w - q3;
            l0 = fmaf(e0, e0, l0); l1 = fmaf(e1, e1, l1);
            l2 = fmaf(e2, e2, l2); l3 = fmaf(e3, e3, l3);
        }
        float s = (l0 + l1) + (l2 + l3);
#pragma unroll
        for (int off = 32; off > 0; off >>= 1) s += __shfl_down(s, off);
        if (lane == 0) wsum[w] = s;
    }
    __syncthreads();
    if (tid == 0) {
        float t = 0.f;
#pragma unroll
        for (int i = 0; i < 8; ++i) t += wsum[i];
        atomicAdd(loss_acc, t);
    }
}

extern "C" void kernel_launch(void* const* d_in, const int* in_sizes, int n_in,
                              void* d_out, int out_size, void* d_ws, size_t ws_size,
                              hipStream_t stream) {
    const float* qin = (const float*)d_in[0]; // (32,64,64,64) f32
    const float* cb = (const float*)d_in[1];  // (512,64) f32
    float* out = (float*)d_out;
    float* loss_out = out + NQ;
    float* idx_out = out + NQ + 1;

    _Float16* blob = (_Float16*)d_ws;                       // 131072 B
    float* shalfg = (float*)((char*)d_ws + 512 * 128 * 2);  // 2048 B

    init_kernel<<<1, 1, 0, stream>>>(loss_out);
    prep_kernel<<<K_CODES, 64, 0, stream>>>(cb, blob, shalfg);
    vq_main<<<NPTS / BPTS, 512, 0, stream>>>(qin, cb, blob, shalfg, out, loss_out, idx_out);
    finalize_kernel<<<1, 1, 0, stream>>>(loss_out);
}

// Round 13
// 74.871 us; speedup vs baseline: 4.4764x; 4.4764x over previous
//
#include <hip/hip_runtime.h>
#include <math.h>

#define K_CODES 512
#define DIM 64
#define NPTS (32 * 4096)   // 131072 points
#define NQ (NPTS * DIM)    // 8388608 quant_out elements
#define BPTS 256           // points per block
#define TAU 2.0e-3f        // rescue margin >> worst-case split-f16 error (~5.5e-4)

typedef _Float16 f16x8 __attribute__((ext_vector_type(8)));
typedef float f32x4 __attribute__((ext_vector_type(4)));

// d_out layout (floats): [quant_out: 8388608][loss: 1][indices-as-float: 131072]
// d_ws layout: [blob: 131072B][shalf: 512 f32]

__global__ void init_kernel(float* __restrict__ loss) { loss[0] = 0.0f; }
__global__ void finalize_kernel(float* __restrict__ loss) {
    loss[0] = 1.2f * loss[0] / 8388608.0f; // (1+BETA)*mean
}

// Fragment-ready split-f16 codebook (identical to r11/r12's proven layout).
__global__ __launch_bounds__(64) void prep_kernel(const float* __restrict__ cb,
                                                  _Float16* __restrict__ blob,
                                                  float* __restrict__ shalfg) {
    int k = blockIdx.x, d = threadIdx.x;
    float e = cb[k * DIM + d];
    _Float16 hi = (_Float16)e;
    _Float16 lo = (_Float16)(e - (float)hi);
    int cf = k >> 4, col = k & 15;
    int q = d >> 5, dd = d & 31, kg = dd >> 3, j = dd & 7;
    size_t base = ((size_t)(cf * 4 + q) * 64 + (kg * 16 + col)) * 8 + j;
    blob[base] = hi;
    blob[base + 2 * 64 * 8] = lo;
    float s = e * e;
#pragma unroll
    for (int m = 32; m; m >>= 1) s += __shfl_xor(s, m);
    if (d == 0) shalfg[k] = 0.5f * s;
}

// 512 blocks x 512 thr (8 waves). Wave = 32 points, scans all 512 codes via
// MFMA on L2-resident frag blob. Near-ties rescued WAVE-PARALLEL in f32.
// launch_bounds(512,1): no VGPR cap -> no spill (r12's (512,4) forced 64 VGPR
// and 580MB of scratch traffic).
__global__ __launch_bounds__(512, 1) void vq_main(const float* __restrict__ qin,
                                                  const float* __restrict__ cb,
                                                  const _Float16* __restrict__ blob,
                                                  const float* __restrict__ shalfg,
                                                  float* __restrict__ out,
                                                  float* __restrict__ loss_acc,
                                                  float* __restrict__ idx_out) {
    __shared__ float shs[K_CODES];
    __shared__ int sfinal[BPTS];
    __shared__ float wsum[8];

    const int tid = threadIdx.x, lane = tid & 63, w = tid >> 6;
    const int row16 = lane & 15, kg = lane >> 4;
    const int wp = w * 32;
    const int n0 = blockIdx.x * BPTS;
    const int b = n0 >> 12, hw0 = n0 & 4095;
    const float* qbase = qin + ((size_t)b << 18) + hw0;
    const f16x8* blp = (const f16x8*)blob + lane;

    shs[tid] = shalfg[tid];

    // ---- A-frags in registers (hi/lo split on the fly); 2 row-frags ----
    f16x8 ah0[2], ah1[2], al0[2], al1[2];
#pragma unroll
    for (int rr = 0; rr < 2; ++rr) {
        const float* xb = qbase + (wp + rr * 16 + row16);
#pragma unroll
        for (int j = 0; j < 8; ++j) {
            float xa = xb[(size_t)(kg * 8 + j) << 12];
            float xc = xb[(size_t)(32 + kg * 8 + j) << 12];
            _Float16 ha = (_Float16)xa, hc = (_Float16)xc;
            ah0[rr][j] = ha; al0[rr][j] = (_Float16)(xa - (float)ha);
            ah1[rr][j] = hc; al1[rr][j] = (_Float16)(xc - (float)hc);
        }
    }
    __syncthreads(); // shs ready

    float b1[8], b2[8];
    int k1[8];
#pragma unroll
    for (int sl = 0; sl < 8; ++sl) { b1[sl] = -INFINITY; b2[sl] = -INFINITY; k1[sl] = 0; }

    // software-prefetch B-frags one cf ahead
    f16x8 nb0 = blp[0 * 64], nb1 = blp[1 * 64], nb2v = blp[2 * 64], nb3 = blp[3 * 64];
#pragma unroll 1
    for (int cf = 0; cf < 32; ++cf) {
        f16x8 bh0 = nb0, bh1 = nb1, bL0 = nb2v, bL1 = nb3;
        if (cf + 1 < 32) {
            nb0 = blp[((cf + 1) * 4 + 0) * 64];
            nb1 = blp[((cf + 1) * 4 + 1) * 64];
            nb2v = blp[((cf + 1) * 4 + 2) * 64];
            nb3 = blp[((cf + 1) * 4 + 3) * 64];
        }
        float sh = shs[cf * 16 + row16];
        f32x4 ini = {-sh, -sh, -sh, -sh};
        f32x4 ac0 = ini, ac1 = ini;
        ac0 = __builtin_amdgcn_mfma_f32_16x16x32_f16(ah0[0], bh0, ac0, 0, 0, 0);
        ac1 = __builtin_amdgcn_mfma_f32_16x16x32_f16(ah0[1], bh0, ac1, 0, 0, 0);
        ac0 = __builtin_amdgcn_mfma_f32_16x16x32_f16(ah1[0], bh1, ac0, 0, 0, 0);
        ac1 = __builtin_amdgcn_mfma_f32_16x16x32_f16(ah1[1], bh1, ac1, 0, 0, 0);
        ac0 = __builtin_amdgcn_mfma_f32_16x16x32_f16(al0[0], bh0, ac0, 0, 0, 0);
        ac1 = __builtin_amdgcn_mfma_f32_16x16x32_f16(al0[1], bh0, ac1, 0, 0, 0);
        ac0 = __builtin_amdgcn_mfma_f32_16x16x32_f16(al1[0], bh1, ac0, 0, 0, 0);
        ac1 = __builtin_amdgcn_mfma_f32_16x16x32_f16(al1[1], bh1, ac1, 0, 0, 0);
        ac0 = __builtin_amdgcn_mfma_f32_16x16x32_f16(ah0[0], bL0, ac0, 0, 0, 0);
        ac1 = __builtin_amdgcn_mfma_f32_16x16x32_f16(ah0[1], bL0, ac1, 0, 0, 0);
        ac0 = __builtin_amdgcn_mfma_f32_16x16x32_f16(ah1[0], bL1, ac0, 0, 0, 0);
        ac1 = __builtin_amdgcn_mfma_f32_16x16x32_f16(ah1[1], bL1, ac1, 0, 0, 0);
        int kglob = cf * 16 + row16;
#define UPD(RR, AC)                                               \
        {                                                         \
            _Pragma("unroll") for (int r = 0; r < 4; ++r) {       \
                float s = (AC)[r];                                \
                int sl = (RR) * 4 + r;                            \
                bool c1 = s > b1[sl];                             \
                bool c2 = s > b2[sl];                             \
                b2[sl] = c1 ? b1[sl] : (c2 ? s : b2[sl]);         \
                b1[sl] = c1 ? s : b1[sl];                         \
                k1[sl] = c1 ? kglob : k1[sl];                     \
            }                                                     \
        }
        UPD(0, ac0) UPD(1, ac1)
#undef UPD
    }

    // reduce top-2 across the 16 col-lanes (butterfly -> uniform per group)
#pragma unroll
    for (int m = 1; m <= 8; m <<= 1) {
#pragma unroll
        for (int sl = 0; sl < 8; ++sl) {
            float ob1 = __shfl_xor(b1[sl], m);
            float ob2 = __shfl_xor(b2[sl], m);
            int ok1 = __shfl_xor(k1[sl], m);
            float nb2x = fmaxf(fminf(b1[sl], ob1), fmaxf(b2[sl], ob2));
            bool take = (ob1 > b1[sl]) || (ob1 == b1[sl] && ok1 < k1[sl]);
            b1[sl] = take ? ob1 : b1[sl];
            k1[sl] = take ? ok1 : k1[sl];
            b2[sl] = nb2x;
        }
    }

    // provisional writes + WAVE-PARALLEL rescue of flagged near-ties
#pragma unroll 1
    for (int sl = 0; sl < 8; ++sl) {
        bool fl = (b1[sl] - b2[sl]) < TAU;
        int pt = wp + (sl >> 2) * 16 + kg * 4 + (sl & 3);
        if (row16 == 0 && !fl) {
            sfinal[pt] = k1[sl];
            idx_out[n0 + pt] = (float)k1[sl];
        }
        unsigned long long mask = __ballot(fl && row16 == 0);
        while (mask) {
            int src = __ffsll((long long)mask) - 1;
            mask &= mask - 1;
            int rpt = wp + (sl >> 2) * 16 + ((src >> 4) << 2) + (sl & 3);
            const float* qx = qbase + rpt;
            float x[DIM];
#pragma unroll
            for (int d = 0; d < DIM; ++d) x[d] = qx[(size_t)d << 12]; // uniform
            float bs = -INFINITY;
            int bi = 0;
#pragma unroll 1
            for (int i = 0; i < 8; ++i) { // lane's codes: k = i*64+lane
                int k = i * 64 + lane;
                const float4* c4 = (const float4*)(cb + (size_t)k * DIM);
                float d0 = 0.f, d1 = 0.f, d2 = 0.f, d3 = 0.f;
#pragma unroll
                for (int i2 = 0; i2 < 16; ++i2) {
                    float4 c = c4[i2];
                    d0 = fmaf(x[4 * i2 + 0], c.x, d0);
                    d1 = fmaf(x[4 * i2 + 1], c.y, d1);
                    d2 = fmaf(x[4 * i2 + 2], c.z, d2);
                    d3 = fmaf(x[4 * i2 + 3], c.w, d3);
                }
                float sc = ((d0 + d1) + (d2 + d3)) - shs[k];
                if (sc > bs) { bs = sc; bi = k; } // ascending within lane
            }
#pragma unroll
            for (int m = 1; m < 64; m <<= 1) { // min-k tiebreak => global first-min
                float os = __shfl_xor(bs, m);
                int oi = __shfl_xor(bi, m);
                if (os > bs || (os == bs && oi < bi)) { bs = os; bi = oi; }
            }
            if (lane == 0) {
                sfinal[rpt] = bi;
                idx_out[n0 + rpt] = (float)bi;
            }
        }
    }
    __syncthreads();

    // epilogue: thread t -> point t&255, dim-half t>>8 (32 dims each)
    {
        int p = tid & 255, hh = tid >> 8;
        int ci = sfinal[p];
        const float* crow = cb + (size_t)ci * DIM + hh * 32;
        const float* qrow = qbase + p + ((size_t)(hh * 32) << 12);
        float* orow = out + ((size_t)b << 18) + hw0 + p + ((size_t)(hh * 32) << 12);
        float l0 = 0.f, l1 = 0.f, l2 = 0.f, l3 = 0.f;
#pragma unroll
        for (int d = 0; d < 32; d += 4) {
            float4 v = *(const float4*)(crow + d);
            orow[(size_t)(d + 0) << 12] = v.x;
            orow[(size_t)(d + 1) << 12] = v.y;
            orow[(size_t)(d + 2) << 12] = v.z;
            orow[(size_t)(d + 3) << 12] = v.w;
            float q0 = qrow[(size_t)(d + 0) << 12];
            float q1 = qrow[(size_t)(d + 1) << 12];
            float q2 = qrow[(size_t)(d + 2) << 12];
            float q3 = qrow[(size_t)(d + 3) << 12];
            float e0 = v.x - q0, e1 = v.y - q1, e2 = v.z - q2, e3 = v.w - q3;
            l0 = fmaf(e0, e0, l0); l1 = fmaf(e1, e1, l1);
            l2 = fmaf(e2, e2, l2); l3 = fmaf(e3, e3, l3);
        }
        float s = (l0 + l1) + (l2 + l3);
#pragma unroll
        for (int off = 32; off > 0; off >>= 1) s += __shfl_down(s, off);
        if (lane == 0) wsum[w] = s;
    }
    __syncthreads();
    if (tid == 0) {
        float t = 0.f;
#pragma unroll
        for (int i = 0; i < 8; ++i) t += wsum[i];
        atomicAdd(loss_acc, t);
    }
}

extern "C" void kernel_launch(void* const* d_in, const int* in_sizes, int n_in,
                              void* d_out, int out_size, void* d_ws, size_t ws_size,
                              hipStream_t stream) {
    const float* qin = (const float*)d_in[0]; // (32,64,64,64) f32
    const float* cb = (const float*)d_in[1];  // (512,64) f32
    float* out = (float*)d_out;
    float* loss_out = out + NQ;
    float* idx_out = out + NQ + 1;

    _Float16* blob = (_Float16*)d_ws;                       // 131072 B
    float* shalfg = (float*)((char*)d_ws + 512 * 128 * 2);  // 2048 B

    init_kernel<<<1, 1, 0, stream>>>(loss_out);
    prep_kernel<<<K_CODES, 64, 0, stream>>>(cb, blob, shalfg);
    vq_main<<<NPTS / BPTS, 512, 0, stream>>>(qin, cb, blob, shalfg, out, loss_out, idx_out);
    finalize_kernel<<<1, 1, 0, stream>>>(loss_out);
}